// Round 4
// baseline (316.557 us; speedup 1.0000x reference)
//
#include <hip/hip_runtime.h>
#include <hip/hip_bf16.h>

// SeqAttention: out = (Q K^T) V  ==  Q (K^T V)   [softmax + key_pe are dead code]
// B=8, M=2048, L=2048, H=1024. fp32 in/out; bf16 MFMA internal.
//
// R4 structure (3 launches):
//   1. transpose_cvt2: K,V fp32 [B,L,H] -> bf16 Kt,Vt [B,H,L]  (one launch, z=16)
//   2. GEMM1: W[b][j][h] = sum_l Vt[j][l]*Kt[h][l]  (bf16 out)   [R3-verified]
//   3. GEMM2: O[b][m][j] = sum_h Q[m][h]*W[j][h]    (fp32 out), Q converted
//      fp32->bf16 inside the A-staging (no separate cvt kernel / Qb buffer).

typedef __bf16 bf16x8 __attribute__((ext_vector_type(8)));
typedef float f32x4 __attribute__((ext_vector_type(4)));
typedef unsigned short u16_t;

#define GLD_LDS16(g, l)                                                        \
  __builtin_amdgcn_global_load_lds(                                            \
      (const __attribute__((address_space(1))) void*)(g),                      \
      (__attribute__((address_space(3))) void*)(l), 16, 0, 0)

static __device__ inline u16_t f2b(float x) {
  __hip_bfloat16 h = __float2bfloat16(x);
  u16_t u;
  __builtin_memcpy(&u, &h, 2);
  return u;
}
static __device__ inline unsigned pack2(float a, float b) {
  return (unsigned)f2b(a) | ((unsigned)f2b(b) << 16);
}

// ---------------------------------------------------------------------------
// fp32 [L,H] -> bf16 [H,L]. z<8: K-batch z; z>=8: V-batch z-8.
// u32 l-pair LDS layout [64 h][33 u32], both phases <=2-way banked (free).
__global__ __launch_bounds__(256) void transpose_cvt2(
    const float* __restrict__ Kin, const float* __restrict__ Vin,
    u16_t* __restrict__ Kt, u16_t* __restrict__ Vt, int L, int Hd) {
  __shared__ unsigned tile[64 * 33];
  const int bz = blockIdx.z;
  const float* in = (bz < 8) ? Kin : Vin;
  u16_t* out = (bz < 8) ? Kt : Vt;
  const int batch = bz & 7;
  in  += (size_t)batch * (size_t)L * Hd;
  out += (size_t)batch * (size_t)L * Hd;
  const int h0 = blockIdx.x * 64;
  const int l0 = blockIdx.y * 64;

  // Phase 1: load (l, l+1) x 4h, pack pairs, write 4 u32 per iter.
  const int h4 = (threadIdx.x & 15) * 4;
  const int lp0 = threadIdx.x >> 4;  // 0..15
#pragma unroll
  for (int it = 0; it < 2; ++it) {
    const int lp = lp0 + 16 * it;  // 0..31
    const int l = 2 * lp;
    const float4 f0 = *(const float4*)(in + (size_t)(l0 + l) * Hd + h0 + h4);
    const float4 f1 = *(const float4*)(in + (size_t)(l0 + l + 1) * Hd + h0 + h4);
    tile[(h4 + 0) * 33 + lp] = pack2(f0.x, f1.x);
    tile[(h4 + 1) * 33 + lp] = pack2(f0.y, f1.y);
    tile[(h4 + 2) * 33 + lp] = pack2(f0.z, f1.z);
    tile[(h4 + 3) * 33 + lp] = pack2(f0.w, f1.w);
  }
  __syncthreads();

  // Phase 2: thread (h = tid>>2, half = tid&3) reads 8 u32 = 16 consecutive l.
  const int h = threadIdx.x >> 2;
  const int half = threadIdx.x & 3;
  unsigned u[8];
#pragma unroll
  for (int j = 0; j < 8; ++j) u[j] = tile[h * 33 + 8 * half + j];
  u16_t* dst = out + (size_t)(h0 + h) * L + l0 + 16 * half;
  *(uint4*)(dst)     = *(const uint4*)(u);
  *(uint4*)(dst + 8) = *(const uint4*)(u + 4);
}

// ---------------------------------------------------------------------------
static __device__ inline void store_c(float* p, float v) { *p = v; }
static __device__ inline void store_c(u16_t* p, float v) { *p = f2b(v); }

// GEMM1 (R3-verified): C[m][n] = sum_k A[m][k]*Bt[n][k], bf16 in, OutT out.
// 1D grid: blockIdx.x = (t<<3)|batch; t -> (tm=t>>3, tn=t&7). N must be 1024.
// LDS: As[row][slot*8..], slot = chunk ^ (row&7)  (BK=64, 8 chunks/row).
template <typename OutT>
__global__ __launch_bounds__(256) void gemm_bt_128(
    const u16_t* __restrict__ A, const u16_t* __restrict__ Bt,
    OutT* __restrict__ C, int M, int N, int K, long sA, long sB, long sC) {
  __shared__ __align__(16) u16_t As[128 * 64];
  __shared__ __align__(16) u16_t Bs[128 * 64];

  const int batch = blockIdx.x & 7;
  const int t = blockIdx.x >> 3;
  const int m0 = (t >> 3) * 128;
  const int n0 = (t & 7) * 128;

  A  += (size_t)batch * (size_t)sA;
  Bt += (size_t)batch * (size_t)sB;
  C  += (size_t)batch * (size_t)sC;

  const int tid = threadIdx.x;
  const int lane = tid & 63;
  const int w  = tid >> 6;
  const int wm = w & 1;
  const int wn = w >> 1;
  const int s  = lane & 15;
  const int q  = lane >> 4;

  const u16_t* gA[4];
  const u16_t* gB[4];
  u16_t* lA[4];
  u16_t* lB[4];
#pragma unroll
  for (int j = 0; j < 4; ++j) {
    const int i = tid + 256 * j;
    const int row = i >> 3;
    const int gchunk = (i & 7) ^ (row & 7);
    gA[j] = A  + (size_t)(m0 + row) * K + gchunk * 8;
    gB[j] = Bt + (size_t)(n0 + row) * K + gchunk * 8;
    lA[j] = As + i * 8;
    lB[j] = Bs + i * 8;
  }

  f32x4 acc[4][4];
#pragma unroll
  for (int r = 0; r < 4; ++r)
#pragma unroll
    for (int c = 0; c < 4; ++c) acc[r][c] = (f32x4){0.f, 0.f, 0.f, 0.f};

  const int s7 = s & 7;

  for (int k0 = 0; k0 < K; k0 += 64) {
#pragma unroll
    for (int j = 0; j < 4; ++j) {
      GLD_LDS16(gA[j] + k0, lA[j]);
      GLD_LDS16(gB[j] + k0, lB[j]);
    }
    __syncthreads();

#pragma unroll
    for (int kk = 0; kk < 2; ++kk) {
      const int slot = (kk * 4 + q) ^ s7;
      bf16x8 af[4], bfr[4];
#pragma unroll
      for (int r = 0; r < 4; ++r)
        af[r] = *(const bf16x8*)(As + (64 * wm + 16 * r + s) * 64 + slot * 8);
#pragma unroll
      for (int c = 0; c < 4; ++c)
        bfr[c] = *(const bf16x8*)(Bs + (64 * wn + 16 * c + s) * 64 + slot * 8);
#pragma unroll
      for (int r = 0; r < 4; ++r)
#pragma unroll
        for (int c = 0; c < 4; ++c)
          acc[r][c] = __builtin_amdgcn_mfma_f32_16x16x32_bf16(af[r], bfr[c],
                                                              acc[r][c], 0, 0, 0);
    }
    __syncthreads();
  }

#pragma unroll
  for (int r = 0; r < 4; ++r) {
#pragma unroll
    for (int c = 0; c < 4; ++c) {
      const int col = n0 + 64 * wn + 16 * c + s;
#pragma unroll
      for (int e = 0; e < 4; ++e) {
        const int row = m0 + 64 * wm + 16 * r + q * 4 + e;
        store_c(&C[(size_t)row * N + col], acc[r][c][e]);
      }
    }
  }
}

// ---------------------------------------------------------------------------
// GEMM2: O[m][n] = sum_k Q[m][k]*W[n][k]; Q fp32 (converted in staging), W bf16.
// Same tile/swizzle as gemm_bt_128; A staged via explicit load+cvt+ds_write_b128
// at the SAME swizzled addresses (write pattern = lane-consecutive 16B -> no
// bank conflicts). N must be 1024.
__global__ __launch_bounds__(256) void gemm2_qf32(
    const float* __restrict__ Af, const u16_t* __restrict__ Bt,
    float* __restrict__ C, int M, int N, int K, long sA, long sB, long sC) {
  __shared__ __align__(16) u16_t As[128 * 64];
  __shared__ __align__(16) u16_t Bs[128 * 64];

  const int batch = blockIdx.x & 7;
  const int t = blockIdx.x >> 3;
  const int m0 = (t >> 3) * 128;
  const int n0 = (t & 7) * 128;

  Af += (size_t)batch * (size_t)sA;
  Bt += (size_t)batch * (size_t)sB;
  C  += (size_t)batch * (size_t)sC;

  const int tid = threadIdx.x;
  const int lane = tid & 63;
  const int w  = tid >> 6;
  const int wm = w & 1;
  const int wn = w >> 1;
  const int s  = lane & 15;
  const int q  = lane >> 4;

  const float* gA[4];
  const u16_t* gB[4];
  uint4* lA[4];
  u16_t* lB[4];
#pragma unroll
  for (int j = 0; j < 4; ++j) {
    const int i = tid + 256 * j;
    const int row = i >> 3;
    const int gchunk = (i & 7) ^ (row & 7);
    gA[j] = Af + (size_t)(m0 + row) * K + gchunk * 8;
    gB[j] = Bt + (size_t)(n0 + row) * K + gchunk * 8;
    lA[j] = (uint4*)(As + i * 8);
    lB[j] = Bs + i * 8;
  }

  f32x4 acc[4][4];
#pragma unroll
  for (int r = 0; r < 4; ++r)
#pragma unroll
    for (int c = 0; c < 4; ++c) acc[r][c] = (f32x4){0.f, 0.f, 0.f, 0.f};

  const int s7 = s & 7;

  for (int k0 = 0; k0 < K; k0 += 64) {
#pragma unroll
    for (int j = 0; j < 4; ++j) GLD_LDS16(gB[j] + k0, lB[j]);
    float4 f0[4], f1[4];
#pragma unroll
    for (int j = 0; j < 4; ++j) {
      f0[j] = *(const float4*)(gA[j] + k0);
      f1[j] = *(const float4*)(gA[j] + k0 + 4);
    }
#pragma unroll
    for (int j = 0; j < 4; ++j) {
      uint4 wv;
      wv.x = pack2(f0[j].x, f0[j].y);
      wv.y = pack2(f0[j].z, f0[j].w);
      wv.z = pack2(f1[j].x, f1[j].y);
      wv.w = pack2(f1[j].z, f1[j].w);
      *lA[j] = wv;
    }
    __syncthreads();

#pragma unroll
    for (int kk = 0; kk < 2; ++kk) {
      const int slot = (kk * 4 + q) ^ s7;
      bf16x8 af[4], bfr[4];
#pragma unroll
      for (int r = 0; r < 4; ++r)
        af[r] = *(const bf16x8*)(As + (64 * wm + 16 * r + s) * 64 + slot * 8);
#pragma unroll
      for (int c = 0; c < 4; ++c)
        bfr[c] = *(const bf16x8*)(Bs + (64 * wn + 16 * c + s) * 64 + slot * 8);
#pragma unroll
      for (int r = 0; r < 4; ++r)
#pragma unroll
        for (int c = 0; c < 4; ++c)
          acc[r][c] = __builtin_amdgcn_mfma_f32_16x16x32_bf16(af[r], bfr[c],
                                                              acc[r][c], 0, 0, 0);
    }
    __syncthreads();
  }

#pragma unroll
  for (int r = 0; r < 4; ++r) {
#pragma unroll
    for (int c = 0; c < 4; ++c) {
      const int col = n0 + 64 * wn + 16 * c + s;
#pragma unroll
      for (int e = 0; e < 4; ++e) {
        const int row = m0 + 64 * wm + 16 * r + q * 4 + e;
        C[(size_t)row * N + col] = acc[r][c][e];
      }
    }
  }
}

// ---------------------------------------------------------------------------
extern "C" void kernel_launch(void* const* d_in, const int* in_sizes, int n_in,
                              void* d_out, int out_size, void* d_ws, size_t ws_size,
                              hipStream_t stream) {
  const int B = 8, M = 2048, L = 2048, H = 1024;

  const float* q = (const float*)d_in[0];  // [B,M,H] fp32
  const float* k = (const float*)d_in[1];  // [B,L,H] fp32
  const float* v = (const float*)d_in[2];  // [B,L,H] fp32

  const size_t nKt = (size_t)B * H * L;
  const size_t nW  = (size_t)B * H * H;
  const size_t need = (2 * nKt + nW) * sizeof(u16_t);  // 84 MiB
  if (ws_size < need) return;

  u16_t* Kt = (u16_t*)d_ws;  // [B,H,L] bf16
  u16_t* Vt = Kt + nKt;      // [B,H,L] bf16
  u16_t* W  = Vt + nKt;      // [B,H,H] bf16: W[j][h] = (K^T V)[h][j]

  dim3 tb(256);

  // K and V transpose+convert in one launch.
  transpose_cvt2<<<dim3(H / 64, L / 64, 2 * B), tb, 0, stream>>>(k, v, Kt, Vt, L, H);

  // GEMM1: W[j][h] = sum_l Vt[j][l] * Kt[h][l]   (M=N=1024, K=2048)
  gemm_bt_128<u16_t><<<dim3(B * (H / 128) * (H / 128)), tb, 0, stream>>>(
      Vt, Kt, W, H, H, L, (long)H * L, (long)H * L, (long)H * H);

  // GEMM2: O[m][j] = sum_h Q[m][h] * W[j][h]    (M=2048, N=1024, K=1024)
  gemm2_qf32<<<dim3(B * (M / 128) * (H / 128)), tb, 0, stream>>>(
      q, W, (float*)d_out, M, H, H, (long)M * H, (long)H * H, (long)M * H);
}

// Round 5
// 315.071 us; speedup vs baseline: 1.0047x; 1.0047x over previous
//
#include <hip/hip_runtime.h>
#include <hip/hip_bf16.h>

// SeqAttention: out = (Q K^T) V  ==  Q (K^T V)   [softmax + key_pe are dead code]
// B=8, M=2048, L=2048, H=1024. fp32 in/out; bf16 MFMA internal.
//
// R5 structure (4 launches, all distinct names for profiling):
//   1. transpose_kv: K,V fp32 [B,L,H] -> bf16 Kt,Vt [B,H,L]     (z = 0..15)
//   2. gemm1_kv:  split-L x2: Wh[kh][b][j][h] = sum_{l in half kh} Vt[j][l]*Kt[h][l]
//                 (bf16 out, two half buffers W0,W1; 1024 blocks -> 4 blocks/CU)
//   3. qcvt_wsum: Qb = bf16(Q) (aliases Kt); Wb = bf16(W0+W1) (aliases Vt)
//   4. gemm2_qw:  O[b][m][j] = sum_h Qb[m][h]*Wb[j][h] (fp32 out) — R3-verified form

typedef __bf16 bf16x8 __attribute__((ext_vector_type(8)));
typedef float f32x4 __attribute__((ext_vector_type(4)));
typedef unsigned short u16_t;

#define GLD_LDS16(g, l)                                                        \
  __builtin_amdgcn_global_load_lds(                                            \
      (const __attribute__((address_space(1))) void*)(g),                      \
      (__attribute__((address_space(3))) void*)(l), 16, 0, 0)

static __device__ inline u16_t f2b(float x) {
  __hip_bfloat16 h = __float2bfloat16(x);
  u16_t u;
  __builtin_memcpy(&u, &h, 2);
  return u;
}
static __device__ inline unsigned pack2(float a, float b) {
  return (unsigned)f2b(a) | ((unsigned)f2b(b) << 16);
}
static __device__ inline float b2f(u16_t u) {
  unsigned v = (unsigned)u << 16;
  float f;
  __builtin_memcpy(&f, &v, 4);
  return f;
}

// ---------------------------------------------------------------------------
// fp32 [L,H] -> bf16 [H,L]. z<8: K-batch z; z>=8: V-batch z-8.  (R4-verified)
__global__ __launch_bounds__(256) void transpose_kv(
    const float* __restrict__ Kin, const float* __restrict__ Vin,
    u16_t* __restrict__ Kt, u16_t* __restrict__ Vt, int L, int Hd) {
  __shared__ unsigned tile[64 * 33];
  const int bz = blockIdx.z;
  const float* in = (bz < 8) ? Kin : Vin;
  u16_t* out = (bz < 8) ? Kt : Vt;
  const int batch = bz & 7;
  in  += (size_t)batch * (size_t)L * Hd;
  out += (size_t)batch * (size_t)L * Hd;
  const int h0 = blockIdx.x * 64;
  const int l0 = blockIdx.y * 64;

  const int h4 = (threadIdx.x & 15) * 4;
  const int lp0 = threadIdx.x >> 4;
#pragma unroll
  for (int it = 0; it < 2; ++it) {
    const int lp = lp0 + 16 * it;  // l-pair 0..31
    const int l = 2 * lp;
    const float4 f0 = *(const float4*)(in + (size_t)(l0 + l) * Hd + h0 + h4);
    const float4 f1 = *(const float4*)(in + (size_t)(l0 + l + 1) * Hd + h0 + h4);
    tile[(h4 + 0) * 33 + lp] = pack2(f0.x, f1.x);
    tile[(h4 + 1) * 33 + lp] = pack2(f0.y, f1.y);
    tile[(h4 + 2) * 33 + lp] = pack2(f0.z, f1.z);
    tile[(h4 + 3) * 33 + lp] = pack2(f0.w, f1.w);
  }
  __syncthreads();

  const int h = threadIdx.x >> 2;
  const int half = threadIdx.x & 3;
  unsigned u[8];
#pragma unroll
  for (int j = 0; j < 8; ++j) u[j] = tile[h * 33 + 8 * half + j];
  u16_t* dst = out + (size_t)(h0 + h) * L + l0 + 16 * half;
  *(uint4*)(dst)     = *(const uint4*)(u);
  *(uint4*)(dst + 8) = *(const uint4*)(u + 4);
}

// ---------------------------------------------------------------------------
static __device__ inline void store_c(float* p, float v) { *p = v; }
static __device__ inline void store_c(u16_t* p, float v) { *p = f2b(v); }

// C[m][n] = sum_{k in split kh} A[m][k]*Bt[n][k].  (R3-verified core)
// blockIdx.x = ((kh*Tiles + t) << 3) | batch;  Tiles = 1<<tile_shift;
// t -> (tm = t>>3, tn = t&7); N must be 1024. K = per-split extent, ld = row stride.
// LDS: As[row][slot*8..], slot = chunk ^ (row&7)  (BK=64, 8 chunks/row).
template <typename OutT>
static __device__ inline void gemm_bt_body(
    const u16_t* __restrict__ A, const u16_t* __restrict__ Bt,
    OutT* __restrict__ C, int N, int K, int ldA, int ldB,
    long sA, long sB, long sC, int tile_shift, long sCsplit) {
  __shared__ __align__(16) u16_t As[128 * 64];
  __shared__ __align__(16) u16_t Bs[128 * 64];

  const int batch = blockIdx.x & 7;
  const unsigned u = blockIdx.x >> 3;
  const int kh = (int)(u >> tile_shift);
  const unsigned t = u & ((1u << tile_shift) - 1u);
  const int m0 = (int)(t >> 3) * 128;
  const int n0 = (int)(t & 7) * 128;

  A  += (size_t)batch * (size_t)sA + (size_t)kh * (size_t)K;
  Bt += (size_t)batch * (size_t)sB + (size_t)kh * (size_t)K;
  C  += (size_t)batch * (size_t)sC + (size_t)kh * (size_t)sCsplit;

  const int tid = threadIdx.x;
  const int lane = tid & 63;
  const int w  = tid >> 6;
  const int wm = w & 1;
  const int wn = w >> 1;
  const int s  = lane & 15;
  const int q  = lane >> 4;

  const u16_t* gA[4];
  const u16_t* gB[4];
  u16_t* lA[4];
  u16_t* lB[4];
#pragma unroll
  for (int j = 0; j < 4; ++j) {
    const int i = tid + 256 * j;
    const int row = i >> 3;
    const int gchunk = (i & 7) ^ (row & 7);
    gA[j] = A  + (size_t)(m0 + row) * ldA + gchunk * 8;
    gB[j] = Bt + (size_t)(n0 + row) * ldB + gchunk * 8;
    lA[j] = As + i * 8;
    lB[j] = Bs + i * 8;
  }

  f32x4 acc[4][4];
#pragma unroll
  for (int r = 0; r < 4; ++r)
#pragma unroll
    for (int c = 0; c < 4; ++c) acc[r][c] = (f32x4){0.f, 0.f, 0.f, 0.f};

  const int s7 = s & 7;

  for (int k0 = 0; k0 < K; k0 += 64) {
#pragma unroll
    for (int j = 0; j < 4; ++j) {
      GLD_LDS16(gA[j] + k0, lA[j]);
      GLD_LDS16(gB[j] + k0, lB[j]);
    }
    __syncthreads();

#pragma unroll
    for (int kk = 0; kk < 2; ++kk) {
      const int slot = (kk * 4 + q) ^ s7;
      bf16x8 af[4], bfr[4];
#pragma unroll
      for (int r = 0; r < 4; ++r)
        af[r] = *(const bf16x8*)(As + (64 * wm + 16 * r + s) * 64 + slot * 8);
#pragma unroll
      for (int c = 0; c < 4; ++c)
        bfr[c] = *(const bf16x8*)(Bs + (64 * wn + 16 * c + s) * 64 + slot * 8);
#pragma unroll
      for (int r = 0; r < 4; ++r)
#pragma unroll
        for (int c = 0; c < 4; ++c)
          acc[r][c] = __builtin_amdgcn_mfma_f32_16x16x32_bf16(af[r], bfr[c],
                                                              acc[r][c], 0, 0, 0);
    }
    __syncthreads();
  }

  // C/D layout (m89-verified): col = lane&15, row = (lane>>4)*4 + reg
#pragma unroll
  for (int r = 0; r < 4; ++r) {
#pragma unroll
    for (int c = 0; c < 4; ++c) {
      const int col = n0 + 64 * wn + 16 * c + s;
#pragma unroll
      for (int e = 0; e < 4; ++e) {
        const int row = m0 + 64 * wm + 16 * r + q * 4 + e;
        store_c(&C[(size_t)row * N + col], acc[r][c][e]);
      }
    }
  }
}

// GEMM1: W-halves from Vt,Kt. grid.x = B * 64 * 2 (tile_shift=6, kh in {0,1}).
__global__ __launch_bounds__(256) void gemm1_kv(
    const u16_t* __restrict__ Vt, const u16_t* __restrict__ Kt,
    u16_t* __restrict__ W0, int N, int K, int ld, long sA, long sB, long sC,
    long sCsplit) {
  gemm_bt_body<u16_t>(Vt, Kt, W0, N, K, ld, ld, sA, sB, sC, 6, sCsplit);
}

// GEMM2: O from Qb,Wb. grid.x = B * 128 (tile_shift=7, kh=0).
__global__ __launch_bounds__(256) void gemm2_qw(
    const u16_t* __restrict__ Qb, const u16_t* __restrict__ Wb,
    float* __restrict__ C, int N, int K, long sA, long sB, long sC) {
  gemm_bt_body<float>(Qb, Wb, C, N, K, K, K, sA, sB, sC, 7, 0);
}

// ---------------------------------------------------------------------------
// z=0: Qb = bf16(Q), 512 blocks/batch x 4096 els.  z=1: Wb = bf16(W0+W1),
// 512 blocks/batch x 2048 els.  grid = dim3(512, B, 2).
__global__ __launch_bounds__(256) void qcvt_wsum(
    const float* __restrict__ Q, const u16_t* __restrict__ W0,
    const u16_t* __restrict__ W1, u16_t* __restrict__ Qb,
    u16_t* __restrict__ Wb, size_t nQbatch, size_t nWbatch) {
  const int batch = blockIdx.y;
  if (blockIdx.z == 0) {
    const size_t base = (size_t)batch * nQbatch +
                        (size_t)blockIdx.x * 4096 + threadIdx.x * 16;
    const float* src = Q + base;
    u16_t* dst = Qb + base;
#pragma unroll
    for (int half = 0; half < 2; ++half) {
      const float4 a = *(const float4*)(src + half * 8);
      const float4 b = *(const float4*)(src + half * 8 + 4);
      unsigned o[4] = {pack2(a.x, a.y), pack2(a.z, a.w),
                       pack2(b.x, b.y), pack2(b.z, b.w)};
      *(uint4*)(dst + half * 8) = *(const uint4*)o;
    }
  } else {
    const size_t base = (size_t)batch * nWbatch +
                        (size_t)blockIdx.x * 2048 + threadIdx.x * 8;
    const uint4 u0 = *(const uint4*)(W0 + base);
    const uint4 u1 = *(const uint4*)(W1 + base);
    const u16_t* p0 = (const u16_t*)&u0;
    const u16_t* p1 = (const u16_t*)&u1;
    u16_t o[8];
#pragma unroll
    for (int j = 0; j < 8; ++j) o[j] = f2b(b2f(p0[j]) + b2f(p1[j]));
    *(uint4*)(Wb + base) = *(const uint4*)o;
  }
}

// ---------------------------------------------------------------------------
extern "C" void kernel_launch(void* const* d_in, const int* in_sizes, int n_in,
                              void* d_out, int out_size, void* d_ws, size_t ws_size,
                              hipStream_t stream) {
  const int B = 8, M = 2048, L = 2048, H = 1024;

  const float* q = (const float*)d_in[0];  // [B,M,H] fp32
  const float* k = (const float*)d_in[1];  // [B,L,H] fp32
  const float* v = (const float*)d_in[2];  // [B,L,H] fp32

  const size_t nKt = (size_t)B * H * L;  // 16.78M els
  const size_t nW  = (size_t)B * H * H;  // 8.39M els
  const size_t need = (2 * nKt + 2 * nW) * sizeof(u16_t);  // 100.7 MB
  if (ws_size < need) return;

  u16_t* Kt = (u16_t*)d_ws;  // [B,H,L]; reused as Qb [B,M,H] after gemm1
  u16_t* Vt = Kt + nKt;      // [B,H,L]; reused as Wb [B,H,H] after gemm1
  u16_t* W0 = Vt + nKt;      // [B,H,H] half-L partial 0
  u16_t* W1 = W0 + nW;       // [B,H,H] half-L partial 1
  u16_t* Qb = Kt;
  u16_t* Wb = Vt;

  dim3 tb(256);

  // 1. K,V transpose+convert.
  transpose_kv<<<dim3(H / 64, L / 64, 2 * B), tb, 0, stream>>>(k, v, Kt, Vt, L, H);

  // 2. GEMM1 split-L x2: W{0,1}[j][h] = sum_{half} Vt[j][l]*Kt[h][l]
  gemm1_kv<<<dim3(B * 64 * 2), tb, 0, stream>>>(
      Vt, Kt, W0, H, L / 2, L, (long)H * L, (long)H * L, (long)H * H,
      (long)B * H * H);

  // 3. Qb = bf16(Q); Wb = bf16(W0+W1).
  qcvt_wsum<<<dim3(512, B, 2), tb, 0, stream>>>(
      q, W0, W1, Qb, Wb, (size_t)M * H, (size_t)H * H);

  // 4. GEMM2: O[m][j] = sum_h Qb[m][h]*Wb[j][h]
  gemm2_qw<<<dim3(B * 128), tb, 0, stream>>>(
      Qb, Wb, (float*)d_out, H, H, (long)M * H, (long)H * H, (long)M * H);
}